// Round 9
// baseline (396.713 us; speedup 1.0000x reference)
//
#include <hip/hip_runtime.h>

// contract(off): numpy-emulating fp32 ops (esq, rescue zsq/dist) must round mul
// and add separately. Explicit fmaf/fma and MFMA are unaffected.
#pragma clang fp contract(off)

#define K_CODES 512
#define D_DIM 256
#define NPIX 65536
#define TAU 3e-4f
#define STRA 264   // A LDS row stride in shorts: 528 B, 16B-aligned, 2-way-only read aliasing
// z layout [B=64, D=256, H*W=1024]; pixel n = b*1024 + hw.

typedef __attribute__((ext_vector_type(8))) short bf16x8;
typedef __attribute__((ext_vector_type(4))) float f32x4;

// B fragments pre-packed in wave-lane order (validated r8): index
// ((kc*32 + nb)*64 + lane)*8 holds B[n = nb*16 + (lane&15)][k = kc*32 + (lane>>4)*8 + j].
__device__ unsigned short g_bph[8 * 32 * 64 * 8];  // hi
__device__ unsigned short g_bpl[8 * 32 * 64 * 8];  // lo
__device__ float4 g_cbF4[(D_DIM / 4) * K_CODES];   // fp32 cb for rescue (exact)
__device__ float  g_esq[K_CODES];                  // numpy-pairwise fp32 ||e_k||^2

static __device__ __forceinline__ unsigned short f2bf(float x) {
    unsigned u = __float_as_uint(x);
    return (unsigned short)((u + 0x7FFFu + ((u >> 16) & 1u)) >> 16);   // RNE
}
static __device__ __forceinline__ float bf2f(unsigned short h) {
    return __uint_as_float((unsigned)h << 16);
}

// 16 blocks x 256: thread = (k, kc). Packing parallel over 16 CUs (r8 ran on 2).
__global__ __launch_bounds__(256) void prep_cb(const float* __restrict__ cb) {
    const int t  = blockIdx.x * 256 + threadIdx.x;   // 0..4095
    const int k  = t >> 3;
    const int kc = t & 7;
    const float* row = cb + k * D_DIM;
    const int nb = k >> 4, nl = k & 15;

    #pragma unroll
    for (int quad = 0; quad < 4; ++quad) {
        const int lane = quad * 16 + nl;
        unsigned short h8[8], l8[8];
        #pragma unroll
        for (int j = 0; j < 8; ++j) {
            float x = row[kc * 32 + quad * 8 + j];
            h8[j] = f2bf(x);
            l8[j] = f2bf(x - bf2f(h8[j]));   // x-hi exact (Sterbenz)
        }
        size_t dst = ((size_t)(kc * 32 + nb) * 64 + lane) * 8;
        *(uint4*)&g_bph[dst] = *(uint4*)&h8[0];
        *(uint4*)&g_bpl[dst] = *(uint4*)&l8[0];
    }

    if (kc == 0) {
        for (int dq = 0; dq < D_DIM / 4; ++dq)
            g_cbF4[dq * K_CODES + k] = make_float4(row[4*dq], row[4*dq+1], row[4*dq+2], row[4*dq+3]);
        // e_sq = np.sum(row*row): pairwise n=256 -> p(0:128)+p(128:256); 8 accums each.
        float s[2];
        for (int blk = 0; blk < 2; ++blk) {
            const float* a = row + blk * 128;
            float r[8];
            #pragma unroll
            for (int j = 0; j < 8; ++j) { float x = a[j]; r[j] = x * x; }
            for (int i = 8; i < 128; i += 8)
                #pragma unroll
                for (int j = 0; j < 8; ++j) { float x = a[i + j]; r[j] += x * x; }
            s[blk] = ((r[0] + r[1]) + (r[2] + r[3])) + ((r[4] + r[5]) + (r[6] + r[7]));
        }
        g_esq[k] = s[0] + s[1];
    }
}

// Fused pass 1: block = 512 thr (8 waves), 64 pixels x 512 codes, K' = 768.
// Prologue stages A into LDS (transpose fused). K-loop fully unrolled with
// register double-buffer prefetch of A and B (r8 issued loads and waited
// immediately -> MfmaUtil 25%). Epilogue: validated r6 argmin/flag + INLINE
// exact rescue (r5 body, 1 code/lane per wave) for flagged pixels.
__global__ __launch_bounds__(512) void pass1_fused(const float* __restrict__ z,
                                                   int* __restrict__ out) {
    __shared__ unsigned short Az[2][64 * STRA];   // [0]=hi, [1]=lo ; [px][d]
    __shared__ float s_mn[8][64];
    __shared__ int   s_ixl[8][64];
    __shared__ float s_gm[64];
    __shared__ int   s_gi[64];
    __shared__ int   s_cnt[64];
    __shared__ float s_rm[8];
    __shared__ int   s_ri[8];

    const int lane = threadIdx.x & 63;
    const int w    = __builtin_amdgcn_readfirstlane((int)(threadIdx.x >> 6));
    const int l16  = lane & 15, quad = lane >> 4;
    const int n0   = (int)blockIdx.x * 64;        // 64 | 1024 -> same b

    // ---- Prologue: stage A (validated r8). wave w: d-chunk [w*32,w*32+32), lane = px.
    {
        const float* zb = z + ((size_t)(n0 >> 10) << 18) + (n0 & 1023);
        const int px = lane, dc = w;
        #pragma unroll
        for (int half = 0; half < 2; ++half) {
            float x[16];
            #pragma unroll
            for (int j = 0; j < 16; ++j)
                x[j] = zb[(size_t)(dc * 32 + half * 16 + j) * 1024 + px]; // coalesced
            unsigned short h[16], l[16];
            #pragma unroll
            for (int j = 0; j < 16; ++j) {
                h[j] = f2bf(x[j]);
                l[j] = f2bf(x[j] - bf2f(h[j]));
            }
            const int o = px * STRA + dc * 32 + half * 16;
            *(uint4*)&Az[0][o]     = *(uint4*)&h[0];
            *(uint4*)&Az[0][o + 8] = *(uint4*)&h[8];
            *(uint4*)&Az[1][o]     = *(uint4*)&l[0];
            *(uint4*)&Az[1][o + 8] = *(uint4*)&l[8];
        }
    }
    __syncthreads();

    f32x4 acc[4][4];
    #pragma unroll
    for (int i = 0; i < 4; ++i)
        #pragma unroll
        for (int j = 0; j < 4; ++j)
            acc[i][j] = (f32x4){0.f, 0.f, 0.f, 0.f};

    // ---- K-loop: 24 steps, no barriers, register double-buffer prefetch.
    // seg0: zh*ch, seg1: zh*cl, seg2: zl*ch (identical chain to validated r6/r8).
    auto loadB = [&](int st, int tj) -> bf16x8 {
        const int seg = st >> 3, kc = st & 7;
        const unsigned short* bp = (seg == 1) ? g_bpl : g_bph;
        return *(const bf16x8*)&bp[((size_t)(kc * 32 + w * 4 + tj) * 64 + lane) * 8];
    };
    auto loadA = [&](int st, int ti) -> bf16x8 {
        const int seg = st >> 3, kc = st & 7;
        const unsigned short* As = Az[(seg == 2) ? 1 : 0];
        return *(const bf16x8*)&As[(ti * 16 + l16) * STRA + kc * 32 + quad * 8];
    };

    bf16x8 bcur[4], acur[4];
    #pragma unroll
    for (int x = 0; x < 4; ++x) { bcur[x] = loadB(0, x); acur[x] = loadA(0, x); }

    #pragma unroll
    for (int st = 0; st < 24; ++st) {
        bf16x8 bnxt[4], anxt[4];
        if (st < 23) {
            #pragma unroll
            for (int x = 0; x < 4; ++x) { bnxt[x] = loadB(st + 1, x); anxt[x] = loadA(st + 1, x); }
        }
        #pragma unroll
        for (int ti = 0; ti < 4; ++ti)
            #pragma unroll
            for (int tj = 0; tj < 4; ++tj)
                acc[ti][tj] = __builtin_amdgcn_mfma_f32_16x16x32_bf16(
                    acur[ti], bcur[tj], acc[ti][tj], 0, 0, 0);
        if (st < 23) {
            #pragma unroll
            for (int x = 0; x < 4; ++x) { bcur[x] = bnxt[x]; acur[x] = anxt[x]; }
        }
    }

    // ---- Epilogue (validated r6). C/D: col=lane&15 -> n, row=quad*4+r -> m.
    float esqv[4];
    #pragma unroll
    for (int tj = 0; tj < 4; ++tj) esqv[tj] = g_esq[w * 64 + tj * 16 + l16];
    #pragma unroll
    for (int ti = 0; ti < 4; ++ti)
        #pragma unroll
        for (int tj = 0; tj < 4; ++tj)
            #pragma unroll
            for (int r = 0; r < 4; ++r)
                acc[ti][tj][r] = fmaf(-2.0f, acc[ti][tj][r], esqv[tj]);

    #pragma unroll
    for (int ti = 0; ti < 4; ++ti) {
        #pragma unroll
        for (int r = 0; r < 4; ++r) {
            float bv = __builtin_inff(); int bn = 0x7FFFFFFF;
            #pragma unroll
            for (int tj = 0; tj < 4; ++tj) {
                float s = acc[ti][tj][r];
                int nn = w * 64 + tj * 16 + l16;
                if (s < bv || (s == bv && nn < bn)) { bv = s; bn = nn; }
            }
            #pragma unroll
            for (int off = 1; off <= 8; off <<= 1) {
                float ov = __shfl_xor(bv, off); int on = __shfl_xor(bn, off);
                if (ov < bv || (ov == bv && on < bn)) { bv = ov; bn = on; }
            }
            if (l16 == 0) {
                int m = ti * 16 + quad * 4 + r;
                s_mn[w][m] = bv; s_ixl[w][m] = bn;
            }
        }
    }
    __syncthreads();

    if (threadIdx.x < 64) {
        int m = threadIdx.x;
        float gm = s_mn[0][m]; int gi = s_ixl[0][m];
        #pragma unroll
        for (int q = 1; q < 8; ++q) {
            float v = s_mn[q][m]; int ii = s_ixl[q][m];
            if (v < gm || (v == gm && ii < gi)) { gm = v; gi = ii; }
        }
        s_gm[m] = gm; s_gi[m] = gi; s_cnt[m] = 0;
    }
    __syncthreads();

    #pragma unroll
    for (int ti = 0; ti < 4; ++ti) {
        #pragma unroll
        for (int r = 0; r < 4; ++r) {
            int m = ti * 16 + quad * 4 + r;
            float thr = s_gm[m] + TAU;
            int c = 0;
            #pragma unroll
            for (int tj = 0; tj < 4; ++tj) c += (acc[ti][tj][r] < thr) ? 1 : 0;
            #pragma unroll
            for (int off = 1; off <= 8; off <<= 1) c += __shfl_xor(c, off);
            if (l16 == 0) atomicAdd(&s_cnt[m], c);
        }
    }
    __syncthreads();

    if (threadIdx.x < 64) {
        int m = threadIdx.x;
        if (s_cnt[m] < 2) out[n0 + m] = s_gi[m];   // rescued pixels written below
    }
    __syncthreads();

    // ---- Inline exact rescue (r5-validated formula). s_cnt in LDS -> uniform
    // branch, so __syncthreads inside is legal. Wave w covers code k = w*64+lane.
    for (int m = 0; m < 64; ++m) {
        if (s_cnt[m] < 2) continue;
        const int n = n0 + m;
        const float* zp = z + ((size_t)(n >> 10) << 18) + (n & 1023);

        float zf[4], xsq[4];
        #pragma unroll
        for (int q = 0; q < 4; ++q) zf[q] = zp[(size_t)((q << 6) + lane) << 10];
        #pragma unroll
        for (int q = 0; q < 4; ++q) xsq[q] = zf[q] * zf[q];

        // numpy pairwise zsq via shuffles (bit-exact, validated r5)
        const int j = lane & 7;
        float r0 = __shfl(xsq[0], j);
        #pragma unroll
        for (int t = 1; t < 8; ++t) r0 += __shfl(xsq[0], 8 * t + j);
        #pragma unroll
        for (int t = 0; t < 8; ++t) r0 += __shfl(xsq[1], 8 * t + j);
        float r1 = __shfl(xsq[2], j);
        #pragma unroll
        for (int t = 1; t < 8; ++t) r1 += __shfl(xsq[2], 8 * t + j);
        #pragma unroll
        for (int t = 0; t < 8; ++t) r1 += __shfl(xsq[3], 8 * t + j);
        r0 = r0 + __shfl_xor(r0, 1); r0 = r0 + __shfl_xor(r0, 2); r0 = r0 + __shfl_xor(r0, 4);
        r1 = r1 + __shfl_xor(r1, 1); r1 = r1 + __shfl_xor(r1, 2); r1 = r1 + __shfl_xor(r1, 4);
        const float zsq = r0 + r1;

        // exact fp64 cross for this wave's code (1 code/lane), 2 chains
        double a8a = 0.0, a8b = 0.0;
        const int kk = (w << 6) + lane;
        for (int dq = 0; dq < D_DIM / 4; ++dq) {
            const int d0 = dq * 4;
            double zd0 = (double)__shfl(zf[(d0    ) >> 6], (d0    ) & 63);
            double zd1 = (double)__shfl(zf[(d0 + 1) >> 6], (d0 + 1) & 63);
            double zd2 = (double)__shfl(zf[(d0 + 2) >> 6], (d0 + 2) & 63);
            double zd3 = (double)__shfl(zf[(d0 + 3) >> 6], (d0 + 3) & 63);
            float4 c4 = g_cbF4[dq * K_CODES + kk];   // coalesced 1 KB/wave
            a8a = fma((double)c4.x, zd0, a8a);
            a8a = fma((double)c4.y, zd1, a8a);
            a8b = fma((double)c4.z, zd2, a8b);
            a8b = fma((double)c4.w, zd3, a8b);
        }

        float c32 = (float)(a8a + a8b);
        float t = zsq - 2.0f * c32;
        float dist = t + g_esq[kk];
        float best = dist; int bi = kk;
        #pragma unroll
        for (int off = 32; off; off >>= 1) {
            float ob = __shfl_xor(best, off);
            int   oi = __shfl_xor(bi, off);
            if (ob < best || (ob == best && oi < bi)) { best = ob; bi = oi; }
        }
        if (lane == 0) { s_rm[w] = best; s_ri[w] = bi; }
        __syncthreads();
        if (threadIdx.x == 0) {
            float b0 = s_rm[0]; int i0 = s_ri[0];
            #pragma unroll
            for (int q = 1; q < 8; ++q) {
                float bq = s_rm[q]; int iq = s_ri[q];
                if (bq < b0 || (bq == b0 && iq < i0)) { b0 = bq; i0 = iq; }
            }
            out[n] = i0;
        }
        __syncthreads();
    }
}

extern "C" void kernel_launch(void* const* d_in, const int* in_sizes, int n_in,
                              void* d_out, int out_size, void* d_ws, size_t ws_size,
                              hipStream_t stream) {
    const float* z_e_x    = (const float*)d_in[0];   // [64, 256, 32, 32] fp32
    const float* codebook = (const float*)d_in[1];   // [512, 256] fp32
    int* out = (int*)d_out;                          // [65536] int32

    prep_cb<<<dim3(16), dim3(256), 0, stream>>>(codebook);
    pass1_fused<<<dim3(1024), dim3(512), 0, stream>>>(z_e_x, out);
}

// Round 10
// 228.867 us; speedup vs baseline: 1.7334x; 1.7334x over previous
//
#include <hip/hip_runtime.h>

// contract(off): numpy-emulating fp32 ops (esq, rescue zsq/dist) must round mul
// and add separately. Explicit fmaf/fma and MFMA are unaffected.
#pragma clang fp contract(off)

#define K_CODES 512
#define D_DIM 256
#define NPIX 65536
#define TAU 3e-4f
#define STRA 264   // A LDS row stride in shorts: 528 B, 16B-aligned
// z layout [B=64, D=256, H*W=1024]; pixel n = b*1024 + hw.

typedef __attribute__((ext_vector_type(8))) short bf16x8;
typedef __attribute__((ext_vector_type(4))) float f32x4;

// B fragments pre-packed in wave-lane order (validated r8): index
// ((kc*32 + nb)*64 + lane)*8 holds B[n = nb*16 + (lane&15)][k = kc*32 + (lane>>4)*8 + j].
__device__ unsigned short g_bph[8 * 32 * 64 * 8];  // hi
__device__ unsigned short g_bpl[8 * 32 * 64 * 8];  // lo
__device__ float4 g_cbF4[(D_DIM / 4) * K_CODES];   // fp32 cb for rescue (exact)
__device__ float  g_esq[K_CODES];                  // numpy-pairwise fp32 ||e_k||^2
__device__ int    g_list[NPIX];
__device__ int    g_count;

static __device__ __forceinline__ unsigned short f2bf(float x) {
    unsigned u = __float_as_uint(x);
    return (unsigned short)((u + 0x7FFFu + ((u >> 16) & 1u)) >> 16);   // RNE
}
static __device__ __forceinline__ float bf2f(unsigned short h) {
    return __uint_as_float((unsigned)h << 16);
}

// 16 blocks x 256: thread = (k, kc). Packing parallel over 16 CUs (r8's 2-block
// version was ~80 us of the r8 residual). Numerics validated in r9.
__global__ __launch_bounds__(256) void prep_cb(const float* __restrict__ cb) {
    if (blockIdx.x == 0 && threadIdx.x == 0) g_count = 0;
    const int t  = blockIdx.x * 256 + threadIdx.x;   // 0..4095
    const int k  = t >> 3;
    const int kc = t & 7;
    const float* row = cb + k * D_DIM;
    const int nb = k >> 4, nl = k & 15;

    #pragma unroll
    for (int quad = 0; quad < 4; ++quad) {
        const int lane = quad * 16 + nl;
        unsigned short h8[8], l8[8];
        #pragma unroll
        for (int j = 0; j < 8; ++j) {
            float x = row[kc * 32 + quad * 8 + j];
            h8[j] = f2bf(x);
            l8[j] = f2bf(x - bf2f(h8[j]));   // x-hi exact (Sterbenz)
        }
        size_t dst = ((size_t)(kc * 32 + nb) * 64 + lane) * 8;
        *(uint4*)&g_bph[dst] = *(uint4*)&h8[0];
        *(uint4*)&g_bpl[dst] = *(uint4*)&l8[0];
    }

    if (kc == 0) {
        for (int dq = 0; dq < D_DIM / 4; ++dq)
            g_cbF4[dq * K_CODES + k] = make_float4(row[4*dq], row[4*dq+1], row[4*dq+2], row[4*dq+3]);
        // e_sq = np.sum(row*row): pairwise n=256 -> p(0:128)+p(128:256); 8 accums each.
        float s[2];
        for (int blk = 0; blk < 2; ++blk) {
            const float* a = row + blk * 128;
            float r[8];
            #pragma unroll
            for (int j = 0; j < 8; ++j) { float x = a[j]; r[j] = x * x; }
            for (int i = 8; i < 128; i += 8)
                #pragma unroll
                for (int j = 0; j < 8; ++j) { float x = a[i + j]; r[j] += x * x; }
            s[blk] = ((r[0] + r[1]) + (r[2] + r[3])) + ((r[4] + r[5]) + (r[6] + r[7]));
        }
        g_esq[k] = s[0] + s[1];
    }
}

// Fused pass 1 = r8's validated structure (VGPR 52, no spill) + B-only
// register prefetch one step ahead (~16 extra VGPRs; A stays just-in-time
// from LDS). r9's both-operand prefetch + inline rescue spilled (VGPR 128,
// 264 MB scratch writes) — do NOT re-add either.
__global__ __launch_bounds__(512) void pass1_fused(const float* __restrict__ z,
                                                   int* __restrict__ out) {
    __shared__ unsigned short Az[2][64 * STRA];   // [0]=hi, [1]=lo ; [px][d]
    __shared__ float s_mn[8][64];
    __shared__ int   s_ixl[8][64];
    __shared__ float s_gm[64];
    __shared__ int   s_gi[64];
    __shared__ int   s_cnt[64];

    const int lane = threadIdx.x & 63;
    const int w    = __builtin_amdgcn_readfirstlane((int)(threadIdx.x >> 6));
    const int l16  = lane & 15, quad = lane >> 4;
    const int n0   = (int)blockIdx.x * 64;        // 64 | 1024 -> same b

    // ---- Prologue: stage A (validated r8). wave w: d-chunk [w*32,w*32+32), lane = px.
    {
        const float* zb = z + ((size_t)(n0 >> 10) << 18) + (n0 & 1023);
        const int px = lane, dc = w;
        #pragma unroll
        for (int half = 0; half < 2; ++half) {
            float x[16];
            #pragma unroll
            for (int j = 0; j < 16; ++j)
                x[j] = zb[(size_t)(dc * 32 + half * 16 + j) * 1024 + px]; // coalesced
            unsigned short h[16], l[16];
            #pragma unroll
            for (int j = 0; j < 16; ++j) {
                h[j] = f2bf(x[j]);
                l[j] = f2bf(x[j] - bf2f(h[j]));
            }
            const int o = px * STRA + dc * 32 + half * 16;
            *(uint4*)&Az[0][o]     = *(uint4*)&h[0];
            *(uint4*)&Az[0][o + 8] = *(uint4*)&h[8];
            *(uint4*)&Az[1][o]     = *(uint4*)&l[0];
            *(uint4*)&Az[1][o + 8] = *(uint4*)&l[8];
        }
    }
    __syncthreads();

    f32x4 acc[4][4];
    #pragma unroll
    for (int i = 0; i < 4; ++i)
        #pragma unroll
        for (int j = 0; j < 4; ++j)
            acc[i][j] = (f32x4){0.f, 0.f, 0.f, 0.f};

    // ---- K-loop: 24 steps, no barriers. seg0: zh*ch, seg1: zh*cl, seg2: zl*ch
    // (chain identical to validated r6/r8). B prefetched one step ahead.
    bf16x8 bcur[4];
    #pragma unroll
    for (int tj = 0; tj < 4; ++tj)
        bcur[tj] = *(const bf16x8*)&g_bph[((size_t)(0 * 32 + w * 4 + tj) * 64 + lane) * 8];

    for (int st = 0; st < 24; ++st) {
        const int seg = st >> 3;
        const int kc  = st & 7;
        const unsigned short* As = Az[(seg == 2) ? 1 : 0];

        bf16x8 bnxt[4];
        if (st < 23) {
            const int sp = st + 1;
            const unsigned short* bp = ((sp >> 3) == 1) ? g_bpl : g_bph;
            const int kcn = sp & 7;
            #pragma unroll
            for (int tj = 0; tj < 4; ++tj)   // 1 KB coalesced per wave, L2-hot
                bnxt[tj] = *(const bf16x8*)&bp[((size_t)(kcn * 32 + w * 4 + tj) * 64 + lane) * 8];
        }

        bf16x8 af[4];
        #pragma unroll
        for (int ti = 0; ti < 4; ++ti)
            af[ti] = *(const bf16x8*)&As[(ti * 16 + l16) * STRA + kc * 32 + quad * 8];

        #pragma unroll
        for (int ti = 0; ti < 4; ++ti)
            #pragma unroll
            for (int tj = 0; tj < 4; ++tj)
                acc[ti][tj] = __builtin_amdgcn_mfma_f32_16x16x32_bf16(
                    af[ti], bcur[tj], acc[ti][tj], 0, 0, 0);

        if (st < 23) {
            #pragma unroll
            for (int tj = 0; tj < 4; ++tj) bcur[tj] = bnxt[tj];
        }
    }

    // ---- Epilogue (validated r6/r8). C/D: col=lane&15 -> n, row=quad*4+r -> m.
    float esqv[4];
    #pragma unroll
    for (int tj = 0; tj < 4; ++tj) esqv[tj] = g_esq[w * 64 + tj * 16 + l16];
    #pragma unroll
    for (int ti = 0; ti < 4; ++ti)
        #pragma unroll
        for (int tj = 0; tj < 4; ++tj)
            #pragma unroll
            for (int r = 0; r < 4; ++r)
                acc[ti][tj][r] = fmaf(-2.0f, acc[ti][tj][r], esqv[tj]);

    #pragma unroll
    for (int ti = 0; ti < 4; ++ti) {
        #pragma unroll
        for (int r = 0; r < 4; ++r) {
            float bv = __builtin_inff(); int bn = 0x7FFFFFFF;
            #pragma unroll
            for (int tj = 0; tj < 4; ++tj) {
                float s = acc[ti][tj][r];
                int nn = w * 64 + tj * 16 + l16;
                if (s < bv || (s == bv && nn < bn)) { bv = s; bn = nn; }
            }
            #pragma unroll
            for (int off = 1; off <= 8; off <<= 1) {
                float ov = __shfl_xor(bv, off); int on = __shfl_xor(bn, off);
                if (ov < bv || (ov == bv && on < bn)) { bv = ov; bn = on; }
            }
            if (l16 == 0) {
                int m = ti * 16 + quad * 4 + r;
                s_mn[w][m] = bv; s_ixl[w][m] = bn;
            }
        }
    }
    __syncthreads();

    if (threadIdx.x < 64) {
        int m = threadIdx.x;
        float gm = s_mn[0][m]; int gi = s_ixl[0][m];
        #pragma unroll
        for (int q = 1; q < 8; ++q) {
            float v = s_mn[q][m]; int ii = s_ixl[q][m];
            if (v < gm || (v == gm && ii < gi)) { gm = v; gi = ii; }
        }
        s_gm[m] = gm; s_gi[m] = gi; s_cnt[m] = 0;
    }
    __syncthreads();

    #pragma unroll
    for (int ti = 0; ti < 4; ++ti) {
        #pragma unroll
        for (int r = 0; r < 4; ++r) {
            int m = ti * 16 + quad * 4 + r;
            float thr = s_gm[m] + TAU;
            int c = 0;
            #pragma unroll
            for (int tj = 0; tj < 4; ++tj) c += (acc[ti][tj][r] < thr) ? 1 : 0;
            #pragma unroll
            for (int off = 1; off <= 8; off <<= 1) c += __shfl_xor(c, off);
            if (l16 == 0) atomicAdd(&s_cnt[m], c);
        }
    }
    __syncthreads();

    if (threadIdx.x < 64) {
        int m = threadIdx.x;
        out[n0 + m] = s_gi[m];
        if (s_cnt[m] >= 2) {
            int pos = atomicAdd(&g_count, 1);
            g_list[pos] = n0 + m;
        }
    }
}

// Rescue: numpy-bit-exact (validated r4/r5/r8). One wave per flagged pixel.
// Separate kernel on purpose: r9's inline version spilled pass-1's registers.
__global__ __launch_bounds__(256) void rescue_kernel(const float* __restrict__ z,
                                                     int* __restrict__ out) {
    const int lane = threadIdx.x & 63;
    const int wg   = (int)blockIdx.x * 4 + (int)(threadIdx.x >> 6);
    const int nw   = (int)gridDim.x * 4;
    const int count = g_count;

    for (int it = wg; it < count; it += nw) {
        const int n = g_list[it];
        const float* zp = z + ((size_t)(n >> 10) << 18) + (n & 1023);

        float zf[4], xsq[4];
        #pragma unroll
        for (int q = 0; q < 4; ++q) zf[q] = zp[(size_t)((q << 6) + lane) << 10];
        #pragma unroll
        for (int q = 0; q < 4; ++q) xsq[q] = zf[q] * zf[q];

        // numpy pairwise zsq via shuffles (bit-exact, validated r5)
        const int j = lane & 7;
        float r0 = __shfl(xsq[0], j);
        #pragma unroll
        for (int t = 1; t < 8; ++t) r0 += __shfl(xsq[0], 8 * t + j);
        #pragma unroll
        for (int t = 0; t < 8; ++t) r0 += __shfl(xsq[1], 8 * t + j);
        float r1 = __shfl(xsq[2], j);
        #pragma unroll
        for (int t = 1; t < 8; ++t) r1 += __shfl(xsq[2], 8 * t + j);
        #pragma unroll
        for (int t = 0; t < 8; ++t) r1 += __shfl(xsq[3], 8 * t + j);
        r0 = r0 + __shfl_xor(r0, 1); r0 = r0 + __shfl_xor(r0, 2); r0 = r0 + __shfl_xor(r0, 4);
        r1 = r1 + __shfl_xor(r1, 1); r1 = r1 + __shfl_xor(r1, 2); r1 = r1 + __shfl_xor(r1, 4);
        const float zsq = r0 + r1;

        double a8a[8], a8b[8];
        #pragma unroll
        for (int jj = 0; jj < 8; ++jj) { a8a[jj] = 0.0; a8b[jj] = 0.0; }
        for (int dq = 0; dq < D_DIM / 4; ++dq) {
            const int d0 = dq * 4;
            double zd0 = (double)__shfl(zf[(d0    ) >> 6], (d0    ) & 63);
            double zd1 = (double)__shfl(zf[(d0 + 1) >> 6], (d0 + 1) & 63);
            double zd2 = (double)__shfl(zf[(d0 + 2) >> 6], (d0 + 2) & 63);
            double zd3 = (double)__shfl(zf[(d0 + 3) >> 6], (d0 + 3) & 63);
            #pragma unroll
            for (int jj = 0; jj < 8; ++jj) {
                float4 c4 = g_cbF4[dq * K_CODES + lane + (jj << 6)];
                a8a[jj] = fma((double)c4.x, zd0, a8a[jj]);
                a8a[jj] = fma((double)c4.y, zd1, a8a[jj]);
                a8b[jj] = fma((double)c4.z, zd2, a8b[jj]);
                a8b[jj] = fma((double)c4.w, zd3, a8b[jj]);
            }
        }

        float best = __builtin_inff(); int bi = 0x7FFFFFFF;
        #pragma unroll
        for (int jj = 0; jj < 8; ++jj) {
            int kk = lane + (jj << 6);
            float c32 = (float)(a8a[jj] + a8b[jj]);
            float t = zsq - 2.0f * c32;
            float dist = t + g_esq[kk];
            if (dist < best || (dist == best && kk < bi)) { best = dist; bi = kk; }
        }
        #pragma unroll
        for (int off = 32; off; off >>= 1) {
            float ob = __shfl_xor(best, off);
            int   oi = __shfl_xor(bi, off);
            if (ob < best || (ob == best && oi < bi)) { best = ob; bi = oi; }
        }
        if (lane == 0) out[n] = bi;
    }
}

extern "C" void kernel_launch(void* const* d_in, const int* in_sizes, int n_in,
                              void* d_out, int out_size, void* d_ws, size_t ws_size,
                              hipStream_t stream) {
    const float* z_e_x    = (const float*)d_in[0];   // [64, 256, 32, 32] fp32
    const float* codebook = (const float*)d_in[1];   // [512, 256] fp32
    int* out = (int*)d_out;                          // [65536] int32

    prep_cb<<<dim3(16), dim3(256), 0, stream>>>(codebook);
    pass1_fused<<<dim3(1024), dim3(512), 0, stream>>>(z_e_x, out);
    rescue_kernel<<<dim3(512), dim3(256), 0, stream>>>(z_e_x, out);
}